// Round 4
// baseline (911.838 us; speedup 1.0000x reference)
//
#include <hip/hip_runtime.h>
#include <stdint.h>

#define NB 32      // batch
#define NC 32      // in channels
#define NN 1024    // nodes
#define NT 12      // time
#define NJ (NB*NC*NT)  // 12288
#define NO 32      // out channels
#define TIN 224    // (2*3+1)*32

typedef __attribute__((ext_vector_type(8))) __bf16 bf16x8;
typedef __attribute__((ext_vector_type(4))) float f32x4;
typedef unsigned short u16;
typedef unsigned int u32;

__device__ __forceinline__ u16 f2bf(float f){
  u32 u = __float_as_uint(f);
  u32 r = (u + 0x7FFFu + ((u >> 16) & 1u)) >> 16;   // RNE
  return (u16)r;
}
__device__ __forceinline__ float bflo(u32 v){ return __uint_as_float(v << 16); }
__device__ __forceinline__ float bfhi(u32 v){ return __uint_as_float(v & 0xFFFF0000u); }

typedef const __attribute__((address_space(1))) u32* gp_t;
typedef __attribute__((address_space(3))) u32* lp_t;
__device__ __forceinline__ void gll16(const void* g, void* l){
  __builtin_amdgcn_global_load_lds((gp_t)g, (lp_t)l, 16, 0, 0);
}

// ---------- prep adj: At[z][m][n] = bf16(adj_z[n][m]) ----------
__global__ __launch_bounds__(256) void k_prep_adj(const float* __restrict__ a0,
      const float* __restrict__ a1, const float* __restrict__ a2, u16* __restrict__ At){
  __shared__ float tile[32][33];
  const float* A = (blockIdx.z==0) ? a0 : (blockIdx.z==1 ? a1 : a2);
  int n0 = blockIdx.x*32, m0 = blockIdx.y*32;
  int tx = threadIdx.x, ty = threadIdx.y;  // block (32,8)
  #pragma unroll
  for (int r=0;r<4;r++)
    tile[ty + 8*r][tx] = A[(size_t)(n0 + ty + 8*r)*NN + m0 + tx];
  __syncthreads();
  u16* dst = At + (size_t)blockIdx.z*NN*NN;
  #pragma unroll
  for (int r=0;r<4;r++)
    dst[(size_t)(m0 + ty + 8*r)*NN + n0 + tx] = f2bf(tile[tx][ty + 8*r]);
}

// ---------- prep x (coalesced): Zt[j][n] = bf16(x[p,n,t]), j = p*12+t ----------
__global__ __launch_bounds__(256) void k_prep_x2(const float* __restrict__ x, u16* __restrict__ Zt){
  __shared__ float tl[64][13];
  int p = blockIdx.y, n0 = blockIdx.x*64;
  const float* xp = x + (size_t)p*NN*NT + (size_t)n0*NT; // 768 consecutive floats
  int tid = threadIdx.x;
  #pragma unroll
  for (int k=0;k<3;k++){
    int e = tid + k*256;
    float v = xp[e];
    tl[e/12][e%12] = v;
  }
  __syncthreads();
  #pragma unroll
  for (int k=0;k<3;k++){
    int e = tid + k*256;
    int t = e >> 6, nn = e & 63;
    Zt[((size_t)p*NT + t)*NN + n0 + nn] = f2bf(tl[nn][t]);
  }
}

// ---------- GEMM: Out[j][m] = sum_k Amat[m][k] * Bmat[j][k] ----------
#define BKK 64
__global__ __launch_bounds__(256) void k_gemm(const u16* __restrict__ Amat,
                                              const u16* __restrict__ Bmat,
                                              u16* __restrict__ Out){
  __shared__ __align__(16) u16 As[128*BKK];
  __shared__ __align__(16) u16 Bs[128*BKK];
  int tid = threadIdx.x;
  int w = tid >> 6, lane = tid & 63;
  int m0 = blockIdx.y * 128, j0 = blockIdx.x * 128;
  int wr = w >> 1, wc = w & 1;
  int lrow = lane & 15, kgrp = lane >> 4;
  int lr8 = lane >> 3, lc8 = lane & 7;

  f32x4 acc[4][4];
  #pragma unroll
  for (int i=0;i<4;i++)
    #pragma unroll
    for (int jj=0;jj<4;jj++)
      acc[i][jj] = (f32x4){0.f,0.f,0.f,0.f};

  const u16* Abase = Amat + (size_t)m0*1024;
  const u16* Bbase = Bmat + (size_t)j0*1024;

  for (int kt=0; kt<1024/BKK; ++kt){
    int k0 = kt*BKK;
    #pragma unroll
    for (int i=0;i<4;i++){
      int q = w*4 + i;
      int row = q*8 + lr8;
      gll16(Abase + (size_t)row*1024 + k0 + lc8*8, (u16*)As + q*512);
      gll16(Bbase + (size_t)row*1024 + k0 + lc8*8, (u16*)Bs + q*512);
    }
    __syncthreads();
    #pragma unroll
    for (int kk=0; kk<2; ++kk){
      bf16x8 af[4], bfr[4];
      #pragma unroll
      for (int mi=0;mi<4;mi++)
        af[mi] = *reinterpret_cast<const bf16x8*>(&As[(wr*64+mi*16+lrow)*BKK + kk*32 + kgrp*8]);
      #pragma unroll
      for (int ji=0;ji<4;ji++)
        bfr[ji] = *reinterpret_cast<const bf16x8*>(&Bs[(wc*64+ji*16+lrow)*BKK + kk*32 + kgrp*8]);
      #pragma unroll
      for (int mi=0;mi<4;mi++)
        #pragma unroll
        for (int ji=0;ji<4;ji++)
          acc[mi][ji] = __builtin_amdgcn_mfma_f32_16x16x32_bf16(af[mi], bfr[ji], acc[mi][ji], 0, 0, 0);
    }
    __syncthreads();
  }

  #pragma unroll
  for (int mi=0;mi<4;mi++){
    #pragma unroll
    for (int ji=0;ji<4;ji++){
      int jg = j0 + wc*64 + ji*16 + lrow;
      int mg = m0 + wr*64 + mi*16 + kgrp*4;
      ushort4 st;
      st.x = f2bf(acc[mi][ji][0]);
      st.y = f2bf(acc[mi][ji][1]);
      st.z = f2bf(acc[mi][ji][2]);
      st.w = f2bf(acc[mi][ji][3]);
      *reinterpret_cast<ushort4*>(&Out[(size_t)jg*1024 + mg]) = st;
    }
  }
}

// ---------- fused channel mix ----------
// All NS sources share the bf16 [j=(b,c,t)][n] layout (Zt is source 0 in the
// fused tiers). thread = (n-pair p, o-quad og, t-half th); acc = f32x4[6][2]
// (o in vector lanes) -> only 12 vector registers of accumulator state.
// y in/out goes through a 24KB LDS transpose: full-line coalesced float4.
template<int NS>
__global__ __launch_bounds__(512) void k_mix(
    const u16* __restrict__ s0, const u16* __restrict__ s1,
    const u16* __restrict__ s2, const u16* __restrict__ s3,
    const u16* __restrict__ s4, const u16* __restrict__ s5,
    const u16* __restrict__ s6,
    const float* __restrict__ W, const float* __restrict__ bias,
    float* __restrict__ y, int wq0, int first){
  __shared__ float Wt[7][32][32];   // [src][c][o] 28KB (conflict-free)
  __shared__ float X[8][768];       // transpose buffer 24KB
  const u16* srcs[7] = {s0,s1,s2,s3,s4,s5,s6};

  int tid = threadIdx.x;
  int p  = tid & 31;          // n-pair index (n = n0 + 2p, 2p+1)
  int og = (tid >> 5) & 7;    // o-quad: o = og*4 .. og*4+3
  int th = tid >> 8;          // t-half: t = th*6 .. th*6+5
  int n0 = blockIdx.x * 64;
  int b  = blockIdx.y;

  // stage W columns (transposed) into LDS
  for (int i = tid; i < NS*1024; i += 512){
    int s = i >> 10, c = (i >> 5) & 31, o = i & 31;
    Wt[s][c][o] = W[(size_t)o*TIN + (wq0 + s)*32 + c];
  }

  f32x4 acc[6][2];
  if (first){
    f32x4 bv = { bias[og*4+0], bias[og*4+1], bias[og*4+2], bias[og*4+3] };
    #pragma unroll
    for (int t=0;t<6;t++){ acc[t][0]=bv; acc[t][1]=bv; }
  } else {
    // load current y via LDS transpose (4 rounds, component r of each f32x4)
    #pragma unroll
    for (int r=0;r<4;r++){
      if (r) __syncthreads();
      #pragma unroll
      for (int k=0;k<3;k++){
        int i = tid + k*512;              // 1536 float4 = 6144 floats
        int og2 = i/192, off = (i - og2*192)*4;
        int o = og2*4 + r;
        *reinterpret_cast<f32x4*>(&X[og2][off]) =
          *reinterpret_cast<const f32x4*>(y + ((size_t)(b*NO+o)*NN + n0)*NT + off);
      }
      __syncthreads();
      #pragma unroll
      for (int t=0;t<6;t++)
        #pragma unroll
        for (int nn=0;nn<2;nn++)
          acc[t][nn][r] = X[og][(2*p+nn)*12 + th*6 + t];
    }
  }
  __syncthreads();   // Wt ready (and X rounds complete)

  size_t rowbase = ((size_t)(b*NC + 0)*NT + th*6)*NN + n0 + 2*p;
  #pragma unroll
  for (int s=0;s<NS;s++){
    const u16* hp = srcs[s];
    for (int c=0;c<NC;c++){
      f32x4 w4 = *reinterpret_cast<const f32x4*>(&Wt[s][c][og*4]);
      const u16* cp = hp + rowbase + (size_t)c*NT*NN;
      #pragma unroll
      for (int t=0;t<6;t++){
        u32 v = *reinterpret_cast<const u32*>(cp + (size_t)t*NN);
        float lo = bflo(v), hi = bfhi(v);
        acc[t][0] += w4 * lo;
        acc[t][1] += w4 * hi;
      }
    }
  }

  // store via LDS transpose: 4 rounds, one f32x4 component each
  #pragma unroll
  for (int r=0;r<4;r++){
    __syncthreads();   // previous round's coop reads / compute done
    #pragma unroll
    for (int t=0;t<6;t++)
      #pragma unroll
      for (int nn=0;nn<2;nn++)
        X[og][(2*p+nn)*12 + th*6 + t] = acc[t][nn][r];
    __syncthreads();
    #pragma unroll
    for (int k=0;k<3;k++){
      int i = tid + k*512;
      int og2 = i/192, off = (i - og2*192)*4;
      int o = og2*4 + r;
      *reinterpret_cast<f32x4*>(y + ((size_t)(b*NO+o)*NN + n0)*NT + off) =
        *reinterpret_cast<const f32x4*>(&X[og2][off]);
    }
  }
}

extern "C" void kernel_launch(void* const* d_in, const int* in_sizes, int n_in,
                              void* d_out, int out_size, void* d_ws, size_t ws_size,
                              hipStream_t stream){
  const float* x    = (const float*)d_in[0];
  const float* a0   = (const float*)d_in[1];
  const float* a1   = (const float*)d_in[2];
  const float* a2   = (const float*)d_in[3];
  const float* W    = (const float*)d_in[4];
  const float* bias = (const float*)d_in[5];
  float* y = (float*)d_out;
  (void)in_sizes; (void)n_in; (void)out_size;

  const size_t atB = (size_t)3*NN*NN*2;     // 6.3 MB
  const size_t hB  = (size_t)NJ*NN*2;       // 25.2 MB each

  char* ws = (char*)d_ws;
  u16* At = (u16*)ws;  ws += atB;
  u16* Zt = (u16*)ws;  ws += hB;

  k_prep_adj<<<dim3(32,32,3), dim3(32,8), 0, stream>>>(a0, a1, a2, At);
  k_prep_x2 <<<dim3(NN/64, NB*NC), 256, 0, stream>>>(x, Zt);

  dim3 mixg(NN/64, NB);
  const dim3 gg(NJ/128, NN/128);

  if (ws_size >= atB + 7*hB){
    // tier 1: everything live, single fused mix
    u16* H[6];
    for (int i=0;i<6;i++){ H[i]=(u16*)ws; ws+=hB; }
    for (int g=0; g<3; ++g){
      const u16* Ag = At + (size_t)g*NN*NN;
      k_gemm<<<gg, 256, 0, stream>>>(Ag, Zt, H[2*g]);
      k_gemm<<<gg, 256, 0, stream>>>(Ag, H[2*g], H[2*g+1]);
    }
    k_mix<7><<<mixg, 512, 0, stream>>>(Zt, H[0],H[1],H[2],H[3],H[4],H[5],
                                       W, bias, y, 0, 1);
  } else if (ws_size >= atB + 5*hB){
    // tier 2: 4 H slots, two mix passes
    u16* H[4];
    for (int i=0;i<4;i++){ H[i]=(u16*)ws; ws+=hB; }
    const u16* A0=At; const u16* A1=At+(size_t)NN*NN; const u16* A2=At+(size_t)2*NN*NN;
    k_gemm<<<gg, 256, 0, stream>>>(A0, Zt,  H[0]);
    k_gemm<<<gg, 256, 0, stream>>>(A0, H[0], H[1]);
    k_mix<3><<<mixg, 512, 0, stream>>>(Zt, H[0], H[1], H[0],H[0],H[0],H[0],
                                       W, bias, y, 0, 1);
    k_gemm<<<gg, 256, 0, stream>>>(A1, Zt,  H[2]);
    k_gemm<<<gg, 256, 0, stream>>>(A1, H[2], H[3]);
    k_gemm<<<gg, 256, 0, stream>>>(A2, Zt,  H[0]);
    k_gemm<<<gg, 256, 0, stream>>>(A2, H[0], H[1]);
    k_mix<4><<<mixg, 512, 0, stream>>>(H[2], H[3], H[0], H[1], H[0],H[0],H[0],
                                       W, bias, y, 3, 0);
  } else {
    // tier 3: 2 H slots, three mix passes
    u16* H1 = (u16*)ws;  ws += hB;
    u16* H2 = (u16*)ws;  ws += hB;
    for (int g=0; g<3; ++g){
      const u16* Ag = At + (size_t)g*NN*NN;
      k_gemm<<<gg, 256, 0, stream>>>(Ag, Zt, H1);
      k_gemm<<<gg, 256, 0, stream>>>(Ag, H1, H2);
      if (g==0)
        k_mix<3><<<mixg, 512, 0, stream>>>(Zt, H1, H2, H1,H1,H1,H1, W, bias, y, 0, 1);
      else
        k_mix<2><<<mixg, 512, 0, stream>>>(H1, H2, H1,H1,H1,H1,H1, W, bias, y, 1+2*g, 0);
    }
  }
}

// Round 5
// 574.093 us; speedup vs baseline: 1.5883x; 1.5883x over previous
//
#include <hip/hip_runtime.h>
#include <stdint.h>

#define NB 32      // batch
#define NC 32      // in channels
#define NN 1024    // nodes
#define NT 12      // time
#define NJ (NB*NC*NT)  // 12288
#define NO 32      // out channels
#define TIN 224    // (2*3+1)*32

typedef __attribute__((ext_vector_type(8))) __bf16 bf16x8;
typedef __attribute__((ext_vector_type(4))) float f32x4;
typedef unsigned short u16;
typedef unsigned int u32;

__device__ __forceinline__ u16 f2bf(float f){
  u32 u = __float_as_uint(f);
  u32 r = (u + 0x7FFFu + ((u >> 16) & 1u)) >> 16;   // RNE
  return (u16)r;
}
__device__ __forceinline__ float bf2f(u16 h){
  return __uint_as_float(((u32)h) << 16);
}

typedef const __attribute__((address_space(1))) u32* gp_t;
typedef __attribute__((address_space(3))) u32* lp_t;
__device__ __forceinline__ void gll16(const void* g, void* l){
  __builtin_amdgcn_global_load_lds((gp_t)g, (lp_t)l, 16, 0, 0);
}

// ---------- prep adj: At[z][m][n] = bf16(adj_z[n][m]) ----------
__global__ __launch_bounds__(256) void k_prep_adj(const float* __restrict__ a0,
      const float* __restrict__ a1, const float* __restrict__ a2, u16* __restrict__ At){
  __shared__ float tile[32][33];
  const float* A = (blockIdx.z==0) ? a0 : (blockIdx.z==1 ? a1 : a2);
  int n0 = blockIdx.x*32, m0 = blockIdx.y*32;
  int tx = threadIdx.x, ty = threadIdx.y;  // block (32,8)
  #pragma unroll
  for (int r=0;r<4;r++)
    tile[ty + 8*r][tx] = A[(size_t)(n0 + ty + 8*r)*NN + m0 + tx];
  __syncthreads();
  u16* dst = At + (size_t)blockIdx.z*NN*NN;
  #pragma unroll
  for (int r=0;r<4;r++)
    dst[(size_t)(m0 + ty + 8*r)*NN + n0 + tx] = f2bf(tile[tx][ty + 8*r]);
}

// ---------- prep x (coalesced): Zt[j][n] = bf16(x[p,n,t]), j = p*12+t ----------
__global__ __launch_bounds__(256) void k_prep_x2(const float* __restrict__ x, u16* __restrict__ Zt){
  __shared__ float tl[64][13];
  int p = blockIdx.y, n0 = blockIdx.x*64;
  const float* xp = x + (size_t)p*NN*NT + (size_t)n0*NT; // 768 consecutive floats
  int tid = threadIdx.x;
  #pragma unroll
  for (int k=0;k<3;k++){
    int e = tid + k*256;
    float v = xp[e];
    tl[e/12][e%12] = v;
  }
  __syncthreads();
  #pragma unroll
  for (int k=0;k<3;k++){
    int e = tid + k*256;
    int t = e >> 6, nn = e & 63;
    Zt[((size_t)p*NT + t)*NN + n0 + nn] = f2bf(tl[nn][t]);
  }
}

// ---------- channel pre-mix (commuted 1x1 conv) ----------
// u1 = W[:, (1+2g)*32 + c] . x      (bf16 out)
// v  = W[:, (1+2g)*32+32 + c] . x   (bf16 out)
// g==0 additionally: Zacc = W[:, 0..31] . x + bias  (fp32 out)
__global__ __launch_bounds__(256) void k_cmix(const u16* __restrict__ Zt,
    const float* __restrict__ W, const float* __restrict__ bias,
    u16* __restrict__ U1, u16* __restrict__ V, float* __restrict__ Zacc, int g){
  __shared__ float X[32][64];
  __shared__ float Wl[3][32][32];
  int tid = threadIdx.x;
  int n0 = blockIdx.x*64;
  int bt = blockIdx.y;                 // b*12 + t
  int b = bt / NT, t = bt - b*NT;

  #pragma unroll
  for (int k=0;k<8;k++){
    int i = tid + k*256;
    int c = i >> 6, n = i & 63;
    X[c][n] = bf2f(Zt[((size_t)(b*NC + c)*NT + t)*NN + n0 + n]);
  }
  int nw = (g==0) ? 3 : 2;
  for (int i = tid; i < nw*1024; i += 256){
    int s = i >> 10, o = (i >> 5) & 31, c = i & 31;
    int off = (s==2) ? 0 : ((1+2*g)*32 + s*32);
    Wl[s][o][c] = W[(size_t)o*TIN + off + c];
  }
  __syncthreads();

  int n = tid & 63, cq = tid >> 6;     // wave = 64 n-cols at one o-octet group
  float a0[8], a1[8], a2[8];
  #pragma unroll
  for (int oo=0;oo<8;oo++){ a0[oo]=0.f; a1[oo]=0.f; a2[oo]=0.f; }
  for (int c=0;c<32;c++){
    float xv = X[c][n];
    #pragma unroll
    for (int oo=0;oo<8;oo++){
      a0[oo] += Wl[0][cq*8+oo][c] * xv;
      a1[oo] += Wl[1][cq*8+oo][c] * xv;
    }
    if (g==0){
      #pragma unroll
      for (int oo=0;oo<8;oo++) a2[oo] += Wl[2][cq*8+oo][c] * xv;
    }
  }
  #pragma unroll
  for (int oo=0;oo<8;oo++){
    size_t row = ((size_t)(b*NC + cq*8+oo)*NT + t)*NN + n0 + n;
    U1[row] = f2bf(a0[oo]);
    V[row]  = f2bf(a1[oo]);
    if (g==0) Zacc[row] = a2[oo] + bias[cq*8+oo];
  }
}

// ---------- GEMM with C-in epilogue: Out[j][m] = sum_k A[m][k]B[j][k] + Cin[j][m] ----------
// F32==0: Cin/Out bf16 ; F32==1: Cin/Out fp32 (Cin may alias Out: own-tile RMW only)
#define BKK 64
template<int F32>
__global__ __launch_bounds__(256) void k_gemm_ep(const u16* __restrict__ Amat,
                                                 const u16* __restrict__ Bmat,
                                                 const void* __restrict__ Cin,
                                                 void* __restrict__ Outv){
  __shared__ __align__(16) u16 As[128*BKK];
  __shared__ __align__(16) u16 Bs[128*BKK];
  int tid = threadIdx.x;
  int w = tid >> 6, lane = tid & 63;
  int m0 = blockIdx.y * 128, j0 = blockIdx.x * 128;
  int wr = w >> 1, wc = w & 1;
  int lrow = lane & 15, kgrp = lane >> 4;
  int lr8 = lane >> 3, lc8 = lane & 7;

  f32x4 acc[4][4];
  #pragma unroll
  for (int i=0;i<4;i++)
    #pragma unroll
    for (int jj=0;jj<4;jj++)
      acc[i][jj] = (f32x4){0.f,0.f,0.f,0.f};

  const u16* Abase = Amat + (size_t)m0*1024;
  const u16* Bbase = Bmat + (size_t)j0*1024;

  for (int kt=0; kt<1024/BKK; ++kt){
    int k0 = kt*BKK;
    #pragma unroll
    for (int i=0;i<4;i++){
      int q = w*4 + i;
      int row = q*8 + lr8;
      gll16(Abase + (size_t)row*1024 + k0 + lc8*8, (u16*)As + q*512);
      gll16(Bbase + (size_t)row*1024 + k0 + lc8*8, (u16*)Bs + q*512);
    }
    __syncthreads();
    #pragma unroll
    for (int kk=0; kk<2; ++kk){
      bf16x8 af[4], bfr[4];
      #pragma unroll
      for (int mi=0;mi<4;mi++)
        af[mi] = *reinterpret_cast<const bf16x8*>(&As[(wr*64+mi*16+lrow)*BKK + kk*32 + kgrp*8]);
      #pragma unroll
      for (int ji=0;ji<4;ji++)
        bfr[ji] = *reinterpret_cast<const bf16x8*>(&Bs[(wc*64+ji*16+lrow)*BKK + kk*32 + kgrp*8]);
      #pragma unroll
      for (int mi=0;mi<4;mi++)
        #pragma unroll
        for (int ji=0;ji<4;ji++)
          acc[mi][ji] = __builtin_amdgcn_mfma_f32_16x16x32_bf16(af[mi], bfr[ji], acc[mi][ji], 0, 0, 0);
    }
    __syncthreads();
  }

  #pragma unroll
  for (int mi=0;mi<4;mi++){
    #pragma unroll
    for (int ji=0;ji<4;ji++){
      int jg = j0 + wc*64 + ji*16 + lrow;
      int mg = m0 + wr*64 + mi*16 + kgrp*4;
      if (F32){
        const float4 cv = *reinterpret_cast<const float4*>((const float*)Cin + (size_t)jg*NN + mg);
        float4 st;
        st.x = acc[mi][ji][0] + cv.x;
        st.y = acc[mi][ji][1] + cv.y;
        st.z = acc[mi][ji][2] + cv.z;
        st.w = acc[mi][ji][3] + cv.w;
        *reinterpret_cast<float4*>((float*)Outv + (size_t)jg*NN + mg) = st;
      } else {
        const ushort4 cv = *reinterpret_cast<const ushort4*>((const u16*)Cin + (size_t)jg*NN + mg);
        ushort4 st;
        st.x = f2bf(acc[mi][ji][0] + bf2f(cv.x));
        st.y = f2bf(acc[mi][ji][1] + bf2f(cv.y));
        st.z = f2bf(acc[mi][ji][2] + bf2f(cv.z));
        st.w = f2bf(acc[mi][ji][3] + bf2f(cv.w));
        *reinterpret_cast<ushort4*>((u16*)Outv + (size_t)jg*NN + mg) = st;
      }
    }
  }
}

// ---------- final transpose: y[b,o,n,t] = Zacc[(b*32+o)*12+t][n] ----------
__global__ __launch_bounds__(256) void k_out(const float* __restrict__ Zacc,
                                             float* __restrict__ y){
  __shared__ float tl[12][65];
  int bo = blockIdx.y;                 // b*32 + o
  int n0 = blockIdx.x*64;
  int tid = threadIdx.x;
  #pragma unroll
  for (int k=0;k<3;k++){
    int i = tid + k*256;
    int t = i >> 6, n = i & 63;
    tl[t][n] = Zacc[((size_t)bo*NT + t)*NN + n0 + n];
  }
  __syncthreads();
  float* yp = y + ((size_t)bo*NN + n0)*NT;
  #pragma unroll
  for (int k=0;k<3;k++){
    int i = tid + k*256;
    yp[i] = tl[i % 12][i / 12];
  }
}

extern "C" void kernel_launch(void* const* d_in, const int* in_sizes, int n_in,
                              void* d_out, int out_size, void* d_ws, size_t ws_size,
                              hipStream_t stream){
  const float* x    = (const float*)d_in[0];
  const float* a0   = (const float*)d_in[1];
  const float* a1   = (const float*)d_in[2];
  const float* a2   = (const float*)d_in[3];
  const float* W    = (const float*)d_in[4];
  const float* bias = (const float*)d_in[5];
  float* y = (float*)d_out;
  (void)in_sizes; (void)n_in; (void)out_size; (void)ws_size;

  const size_t atB = (size_t)3*NN*NN*2;     // 6.3 MB
  const size_t hB  = (size_t)NJ*NN*2;       // 25.2 MB

  char* ws = (char*)d_ws;
  u16*   At   = (u16*)ws;   ws += atB;
  u16*   Zt   = (u16*)ws;   ws += hB;
  u16*   U1   = (u16*)ws;   ws += hB;
  u16*   V    = (u16*)ws;   ws += hB;
  u16*   T    = (u16*)ws;   ws += hB;
  float* Zacc = (float*)ws; ws += (size_t)NJ*NN*4;   // fp32 accumulator (50 MB)
  // total ~157 MB; harness provides >=182 MB (verified R4: tier-1 ran)

  k_prep_adj<<<dim3(32,32,3), dim3(32,8), 0, stream>>>(a0, a1, a2, At);
  k_prep_x2 <<<dim3(NN/64, NB*NC), 256, 0, stream>>>(x, Zt);

  const dim3 gg(NJ/128, NN/128);
  for (int g=0; g<3; ++g){
    const u16* Ag = At + (size_t)g*NN*NN;
    k_cmix<<<dim3(NN/64, NB*NT), 256, 0, stream>>>(Zt, W, bias, U1, V, Zacc, g);
    // T = A_g * V + U1        (bf16)
    k_gemm_ep<0><<<gg, 256, 0, stream>>>(Ag, V, U1, T);
    // Zacc = A_g * T + Zacc   (fp32)
    k_gemm_ep<1><<<gg, 256, 0, stream>>>(Ag, T, Zacc, Zacc);
  }
  k_out<<<dim3(NN/64, NB*NO), 256, 0, stream>>>(Zacc, y);
}

// Round 6
// 485.227 us; speedup vs baseline: 1.8792x; 1.1831x over previous
//
#include <hip/hip_runtime.h>
#include <stdint.h>

#define NB 32      // batch
#define NC 32      // in channels
#define NN 1024    // nodes
#define NT 12      // time
#define NJ (NB*NC*NT)  // 12288
#define NO 32      // out channels
#define TIN 224    // (2*3+1)*32

typedef __attribute__((ext_vector_type(8))) __bf16 bf16x8;
typedef __attribute__((ext_vector_type(4))) float f32x4;
typedef unsigned short u16;
typedef unsigned int u32;

__device__ __forceinline__ u16 f2bf(float f){
  u32 u = __float_as_uint(f);
  u32 r = (u + 0x7FFFu + ((u >> 16) & 1u)) >> 16;   // RNE
  return (u16)r;
}
__device__ __forceinline__ float bf2f(u16 h){
  return __uint_as_float(((u32)h) << 16);
}
__device__ __forceinline__ float bflo(u32 v){ return __uint_as_float(v << 16); }
__device__ __forceinline__ float bfhi(u32 v){ return __uint_as_float(v & 0xFFFF0000u); }

typedef const __attribute__((address_space(1))) u32* gp_t;
typedef __attribute__((address_space(3))) u32* lp_t;
__device__ __forceinline__ void gll16(const void* g, void* l){
  __builtin_amdgcn_global_load_lds((gp_t)g, (lp_t)l, 16, 0, 0);
}

// ---------- prep adj: At[z][m][n] = bf16(adj_z[n][m]) ----------
__global__ __launch_bounds__(256) void k_prep_adj(const float* __restrict__ a0,
      const float* __restrict__ a1, const float* __restrict__ a2, u16* __restrict__ At){
  __shared__ float tile[32][33];
  const float* A = (blockIdx.z==0) ? a0 : (blockIdx.z==1 ? a1 : a2);
  int n0 = blockIdx.x*32, m0 = blockIdx.y*32;
  int tx = threadIdx.x, ty = threadIdx.y;  // block (32,8)
  #pragma unroll
  for (int r=0;r<4;r++)
    tile[ty + 8*r][tx] = A[(size_t)(n0 + ty + 8*r)*NN + m0 + tx];
  __syncthreads();
  u16* dst = At + (size_t)blockIdx.z*NN*NN;
  #pragma unroll
  for (int r=0;r<4;r++)
    dst[(size_t)(m0 + ty + 8*r)*NN + n0 + tx] = f2bf(tile[tx][ty + 8*r]);
}

// ---------- prep x (coalesced): Zt[j][n] = bf16(x[p,n,t]), j = p*12+t ----------
__global__ __launch_bounds__(256) void k_prep_x2(const float* __restrict__ x, u16* __restrict__ Zt){
  __shared__ float tl[64][13];
  int p = blockIdx.y, n0 = blockIdx.x*64;
  const float* xp = x + (size_t)p*NN*NT + (size_t)n0*NT; // 768 consecutive floats
  int tid = threadIdx.x;
  #pragma unroll
  for (int k=0;k<3;k++){
    int e = tid + k*256;
    float v = xp[e];
    tl[e/12][e%12] = v;
  }
  __syncthreads();
  #pragma unroll
  for (int k=0;k<3;k++){
    int e = tid + k*256;
    int t = e >> 6, nn = e & 63;
    Zt[((size_t)p*NT + t)*NN + n0 + nn] = f2bf(tl[nn][t]);
  }
}

// ---------- channel pre-mix v2 ----------
// u1 = W1g . x, v = W2g . x (bf16); g==0 also Zacc = Wx . x + bias (fp32).
// Wave-uniform o-octet -> W reads are scalar (s_load, free pipe).
// 2 n per lane -> all vector IO is >=4B coalesced. X staged once in LDS.
template<int G0>
__global__ __launch_bounds__(256) void k_cmix2(const u16* __restrict__ Zt,
    const float* __restrict__ W, const float* __restrict__ bias,
    u16* __restrict__ U1, u16* __restrict__ V, float* __restrict__ Zacc, int g){
  __shared__ u32 X[32][64];   // bf16 n-pairs, 8 KB
  int tid = threadIdx.x;
  int n0 = blockIdx.x*128;
  int bt = blockIdx.y;                 // b*12 + t
  int b = bt / NT, t = bt - b*NT;

  {
    const u16* zb = Zt + ((size_t)(b*NC)*NT + t)*NN + n0;
    #pragma unroll
    for (int k=0;k<8;k++){
      int i = tid + k*256;
      int c = i >> 6, col = i & 63;
      X[c][col] = *reinterpret_cast<const u32*>(zb + (size_t)c*(NT*NN) + 2*col);
    }
  }
  __syncthreads();

  int lane = tid & 63;
  int og = __builtin_amdgcn_readfirstlane(tid >> 6);   // wave-uniform o-octet
  int gb = (1+2*g)*32;

  float aU[8][2], aV[8][2], aZ[8][2];
  #pragma unroll
  for (int oo=0;oo<8;oo++){
    aU[oo][0]=0.f; aU[oo][1]=0.f;
    aV[oo][0]=0.f; aV[oo][1]=0.f;
    aZ[oo][0]=0.f; aZ[oo][1]=0.f;
  }

  #pragma unroll
  for (int c=0;c<32;c++){
    u32 xp = X[c][lane];
    float xl = bflo(xp), xh = bfhi(xp);
    #pragma unroll
    for (int oo=0;oo<8;oo++){
      const float* wrow = W + (size_t)(og*8+oo)*TIN;   // uniform -> s_load
      float w1 = wrow[gb + c];
      float w2 = wrow[gb + 32 + c];
      aU[oo][0] += w1*xl; aU[oo][1] += w1*xh;
      aV[oo][0] += w2*xl; aV[oo][1] += w2*xh;
      if (G0){
        float wx = wrow[c];
        aZ[oo][0] += wx*xl; aZ[oo][1] += wx*xh;
      }
    }
  }

  #pragma unroll
  for (int oo=0;oo<8;oo++){
    int o = og*8+oo;
    size_t row = ((size_t)(b*NC + o)*NT + t)*NN + n0 + 2*lane;
    u32 up = (u32)f2bf(aU[oo][0]) | ((u32)f2bf(aU[oo][1]) << 16);
    u32 vp = (u32)f2bf(aV[oo][0]) | ((u32)f2bf(aV[oo][1]) << 16);
    *reinterpret_cast<u32*>(U1 + row) = up;
    *reinterpret_cast<u32*>(V  + row) = vp;
    if (G0){
      float bv = bias[o];
      float2 z; z.x = aZ[oo][0] + bv; z.y = aZ[oo][1] + bv;
      *reinterpret_cast<float2*>(Zacc + row) = z;
    }
  }
}

// ---------- GEMM with C-in epilogue: Out[j][m] = sum_k A[m][k]B[j][k] + Cin[j][m] ----------
// F32==0: Cin/Out bf16 ; F32==1: Cin/Out fp32 (Cin may alias Out: own-tile RMW only)
#define BKK 64
template<int F32>
__global__ __launch_bounds__(256) void k_gemm_ep(const u16* __restrict__ Amat,
                                                 const u16* __restrict__ Bmat,
                                                 const void* __restrict__ Cin,
                                                 void* __restrict__ Outv){
  __shared__ __align__(16) u16 As[128*BKK];
  __shared__ __align__(16) u16 Bs[128*BKK];
  int tid = threadIdx.x;
  int w = tid >> 6, lane = tid & 63;
  int m0 = blockIdx.y * 128, j0 = blockIdx.x * 128;
  int wr = w >> 1, wc = w & 1;
  int lrow = lane & 15, kgrp = lane >> 4;
  int lr8 = lane >> 3, lc8 = lane & 7;

  f32x4 acc[4][4];
  #pragma unroll
  for (int i=0;i<4;i++)
    #pragma unroll
    for (int jj=0;jj<4;jj++)
      acc[i][jj] = (f32x4){0.f,0.f,0.f,0.f};

  const u16* Abase = Amat + (size_t)m0*1024;
  const u16* Bbase = Bmat + (size_t)j0*1024;

  for (int kt=0; kt<1024/BKK; ++kt){
    int k0 = kt*BKK;
    #pragma unroll
    for (int i=0;i<4;i++){
      int q = w*4 + i;
      int row = q*8 + lr8;
      gll16(Abase + (size_t)row*1024 + k0 + lc8*8, (u16*)As + q*512);
      gll16(Bbase + (size_t)row*1024 + k0 + lc8*8, (u16*)Bs + q*512);
    }
    __syncthreads();
    #pragma unroll
    for (int kk=0; kk<2; ++kk){
      bf16x8 af[4], bfr[4];
      #pragma unroll
      for (int mi=0;mi<4;mi++)
        af[mi] = *reinterpret_cast<const bf16x8*>(&As[(wr*64+mi*16+lrow)*BKK + kk*32 + kgrp*8]);
      #pragma unroll
      for (int ji=0;ji<4;ji++)
        bfr[ji] = *reinterpret_cast<const bf16x8*>(&Bs[(wc*64+ji*16+lrow)*BKK + kk*32 + kgrp*8]);
      #pragma unroll
      for (int mi=0;mi<4;mi++)
        #pragma unroll
        for (int ji=0;ji<4;ji++)
          acc[mi][ji] = __builtin_amdgcn_mfma_f32_16x16x32_bf16(af[mi], bfr[ji], acc[mi][ji], 0, 0, 0);
    }
    __syncthreads();
  }

  #pragma unroll
  for (int mi=0;mi<4;mi++){
    #pragma unroll
    for (int ji=0;ji<4;ji++){
      int jg = j0 + wc*64 + ji*16 + lrow;
      int mg = m0 + wr*64 + mi*16 + kgrp*4;
      if (F32){
        const float4 cv = *reinterpret_cast<const float4*>((const float*)Cin + (size_t)jg*NN + mg);
        float4 st;
        st.x = acc[mi][ji][0] + cv.x;
        st.y = acc[mi][ji][1] + cv.y;
        st.z = acc[mi][ji][2] + cv.z;
        st.w = acc[mi][ji][3] + cv.w;
        *reinterpret_cast<float4*>((float*)Outv + (size_t)jg*NN + mg) = st;
      } else {
        const ushort4 cv = *reinterpret_cast<const ushort4*>((const u16*)Cin + (size_t)jg*NN + mg);
        ushort4 st;
        st.x = f2bf(acc[mi][ji][0] + bf2f(cv.x));
        st.y = f2bf(acc[mi][ji][1] + bf2f(cv.y));
        st.z = f2bf(acc[mi][ji][2] + bf2f(cv.z));
        st.w = f2bf(acc[mi][ji][3] + bf2f(cv.w));
        *reinterpret_cast<ushort4*>((u16*)Outv + (size_t)jg*NN + mg) = st;
      }
    }
  }
}

// ---------- final transpose: y[b,o,n,t] = Zacc[(b*32+o)*12+t][n] ----------
__global__ __launch_bounds__(256) void k_out(const float* __restrict__ Zacc,
                                             float* __restrict__ y){
  __shared__ float tl[12][65];
  int bo = blockIdx.y;                 // b*32 + o
  int n0 = blockIdx.x*64;
  int tid = threadIdx.x;
  #pragma unroll
  for (int k=0;k<3;k++){
    int i = tid + k*256;
    int t = i >> 6, n = i & 63;
    tl[t][n] = Zacc[((size_t)bo*NT + t)*NN + n0 + n];
  }
  __syncthreads();
  float* yp = y + ((size_t)bo*NN + n0)*NT;
  #pragma unroll
  for (int k=0;k<3;k++){
    int i = tid + k*256;
    yp[i] = tl[i % 12][i / 12];
  }
}

extern "C" void kernel_launch(void* const* d_in, const int* in_sizes, int n_in,
                              void* d_out, int out_size, void* d_ws, size_t ws_size,
                              hipStream_t stream){
  const float* x    = (const float*)d_in[0];
  const float* a0   = (const float*)d_in[1];
  const float* a1   = (const float*)d_in[2];
  const float* a2   = (const float*)d_in[3];
  const float* W    = (const float*)d_in[4];
  const float* bias = (const float*)d_in[5];
  float* y = (float*)d_out;
  (void)in_sizes; (void)n_in; (void)out_size; (void)ws_size;

  const size_t atB = (size_t)3*NN*NN*2;     // 6.3 MB
  const size_t hB  = (size_t)NJ*NN*2;       // 25.2 MB

  char* ws = (char*)d_ws;
  u16*   At   = (u16*)ws;   ws += atB;
  u16*   Zt   = (u16*)ws;   ws += hB;
  u16*   U1   = (u16*)ws;   ws += hB;
  u16*   V    = (u16*)ws;   ws += hB;
  u16*   T    = (u16*)ws;   ws += hB;
  float* Zacc = (float*)ws; ws += (size_t)NJ*NN*4;   // fp32 accumulator (50 MB)
  // total ~157 MB; harness provides >=182 MB (verified R4: tier-1 ran)

  k_prep_adj<<<dim3(32,32,3), dim3(32,8), 0, stream>>>(a0, a1, a2, At);
  k_prep_x2 <<<dim3(NN/64, NB*NC), 256, 0, stream>>>(x, Zt);

  const dim3 gg(NJ/128, NN/128);
  for (int g=0; g<3; ++g){
    const u16* Ag = At + (size_t)g*NN*NN;
    if (g==0)
      k_cmix2<1><<<dim3(NN/128, NB*NT), 256, 0, stream>>>(Zt, W, bias, U1, V, Zacc, g);
    else
      k_cmix2<0><<<dim3(NN/128, NB*NT), 256, 0, stream>>>(Zt, W, bias, U1, V, Zacc, g);
    // T = A_g * V + U1        (bf16)
    k_gemm_ep<0><<<gg, 256, 0, stream>>>(Ag, V, U1, T);
    // Zacc = A_g * T + Zacc   (fp32)
    k_gemm_ep<1><<<gg, 256, 0, stream>>>(Ag, T, Zacc, Zacc);
  }
  k_out<<<dim3(NN/64, NB*NO), 256, 0, stream>>>(Zacc, y);
}

// Round 7
// 414.436 us; speedup vs baseline: 2.2002x; 1.1708x over previous
//
#include <hip/hip_runtime.h>
#include <stdint.h>

#define NB 32      // batch
#define NC 32      // in channels
#define NN 1024    // nodes
#define NT 12      // time
#define NJ (NB*NC*NT)  // 12288
#define NO 32      // out channels
#define TIN 224    // (2*3+1)*32
#define HBE ((size_t)NJ*NN)   // elements per [j][n] buffer

typedef __attribute__((ext_vector_type(8))) __bf16 bf16x8;
typedef __attribute__((ext_vector_type(4))) float f32x4;
typedef unsigned short u16;
typedef unsigned int u32;

__device__ __forceinline__ u16 f2bf(float f){
  u32 u = __float_as_uint(f);
  u32 r = (u + 0x7FFFu + ((u >> 16) & 1u)) >> 16;   // RNE
  return (u16)r;
}
__device__ __forceinline__ float bf2f(u16 h){
  return __uint_as_float(((u32)h) << 16);
}
__device__ __forceinline__ float bflo(u32 v){ return __uint_as_float(v << 16); }
__device__ __forceinline__ float bfhi(u32 v){ return __uint_as_float(v & 0xFFFF0000u); }

typedef const __attribute__((address_space(1))) u32* gp_t;
typedef __attribute__((address_space(3))) u32* lp_t;
__device__ __forceinline__ void gll16(const void* g, void* l){
  __builtin_amdgcn_global_load_lds((gp_t)g, (lp_t)l, 16, 0, 0);
}

// ---------- prep adj: At[z][m][n] = bf16(adj_z[n][m]) ----------
__global__ __launch_bounds__(256) void k_prep_adj(const float* __restrict__ a0,
      const float* __restrict__ a1, const float* __restrict__ a2, u16* __restrict__ At){
  __shared__ float tile[32][33];
  const float* A = (blockIdx.z==0) ? a0 : (blockIdx.z==1 ? a1 : a2);
  int n0 = blockIdx.x*32, m0 = blockIdx.y*32;
  int tx = threadIdx.x, ty = threadIdx.y;  // block (32,8)
  #pragma unroll
  for (int r=0;r<4;r++)
    tile[ty + 8*r][tx] = A[(size_t)(n0 + ty + 8*r)*NN + m0 + tx];
  __syncthreads();
  u16* dst = At + (size_t)blockIdx.z*NN*NN;
  #pragma unroll
  for (int r=0;r<4;r++)
    dst[(size_t)(m0 + ty + 8*r)*NN + n0 + tx] = f2bf(tile[tx][ty + 8*r]);
}

// ---------- prep x (coalesced): Zt[j][n] = bf16(x[p,n,t]), j = p*12+t ----------
__global__ __launch_bounds__(256) void k_prep_x2(const float* __restrict__ x, u16* __restrict__ Zt){
  __shared__ float tl[64][13];
  int p = blockIdx.y, n0 = blockIdx.x*64;
  const float* xp = x + (size_t)p*NN*NT + (size_t)n0*NT; // 768 consecutive floats
  int tid = threadIdx.x;
  #pragma unroll
  for (int k=0;k<3;k++){
    int e = tid + k*256;
    float v = xp[e];
    tl[e/12][e%12] = v;
  }
  __syncthreads();
  #pragma unroll
  for (int k=0;k<3;k++){
    int e = tid + k*256;
    int t = e >> 6, nn = e & 63;
    Zt[((size_t)p*NT + t)*NN + n0 + nn] = f2bf(tl[nn][t]);
  }
}

// ---------- batched GEMM: z = adjacency index ----------
// PASS0: D1_z = A_z * Zt ; PASS1: D2_z = A_z * D1_z.  Out[j][m] bf16.
#define BKK 64
template<int PASS>
__global__ __launch_bounds__(256) void k_gemm3(const u16* __restrict__ At,
                                               const u16* __restrict__ ZtB,
                                               u16* __restrict__ Db){
  __shared__ __align__(16) u16 As[128*BKK];
  __shared__ __align__(16) u16 Bs[128*BKK];
  int tid = threadIdx.x;
  int w = tid >> 6, lane = tid & 63;
  int z = blockIdx.z;
  int m0 = blockIdx.y * 128, j0 = blockIdx.x * 128;
  int wr = w >> 1, wc = w & 1;
  int lrow = lane & 15, kgrp = lane >> 4;
  int lr8 = lane >> 3, lc8 = lane & 7;

  const u16* Amat = At + (size_t)z*NN*NN;
  const u16* Bmat = (PASS==0) ? ZtB : (Db + (size_t)(2*z)*HBE);
  u16* Out = Db + (size_t)(PASS==0 ? 2*z : 2*z+1)*HBE;

  f32x4 acc[4][4];
  #pragma unroll
  for (int i=0;i<4;i++)
    #pragma unroll
    for (int jj=0;jj<4;jj++)
      acc[i][jj] = (f32x4){0.f,0.f,0.f,0.f};

  const u16* Abase = Amat + (size_t)m0*1024;
  const u16* Bbase = Bmat + (size_t)j0*1024;

  for (int kt=0; kt<1024/BKK; ++kt){
    int k0 = kt*BKK;
    #pragma unroll
    for (int i=0;i<4;i++){
      int q = w*4 + i;
      int row = q*8 + lr8;
      gll16(Abase + (size_t)row*1024 + k0 + lc8*8, (u16*)As + q*512);
      gll16(Bbase + (size_t)row*1024 + k0 + lc8*8, (u16*)Bs + q*512);
    }
    __syncthreads();
    #pragma unroll
    for (int kk=0; kk<2; ++kk){
      bf16x8 af[4], bfr[4];
      #pragma unroll
      for (int mi=0;mi<4;mi++)
        af[mi] = *reinterpret_cast<const bf16x8*>(&As[(wr*64+mi*16+lrow)*BKK + kk*32 + kgrp*8]);
      #pragma unroll
      for (int ji=0;ji<4;ji++)
        bfr[ji] = *reinterpret_cast<const bf16x8*>(&Bs[(wc*64+ji*16+lrow)*BKK + kk*32 + kgrp*8]);
      #pragma unroll
      for (int mi=0;mi<4;mi++)
        #pragma unroll
        for (int ji=0;ji<4;ji++)
          acc[mi][ji] = __builtin_amdgcn_mfma_f32_16x16x32_bf16(af[mi], bfr[ji], acc[mi][ji], 0, 0, 0);
    }
    __syncthreads();
  }

  #pragma unroll
  for (int mi=0;mi<4;mi++){
    #pragma unroll
    for (int ji=0;ji<4;ji++){
      int jg = j0 + wc*64 + ji*16 + lrow;
      int mg = m0 + wr*64 + mi*16 + kgrp*4;
      ushort4 st;
      st.x = f2bf(acc[mi][ji][0]);
      st.y = f2bf(acc[mi][ji][1]);
      st.z = f2bf(acc[mi][ji][2]);
      st.w = f2bf(acc[mi][ji][3]);
      *reinterpret_cast<ushort4*>(&Out[(size_t)jg*NN + mg]) = st;
    }
  }
}

// ---------- final channel mix, K=224 flat ----------
// Sources s=0..6 = [Zt, D1_0, D2_0, D1_1, D2_1, D1_2, D2_2]; W col = s*32+c
// exactly matches flat c' in 0..223.  Output: bf16 y-intermediate written
// IN-PLACE over Zt (this block stages all its Zt reads to LDS first; other
// blocks touch disjoint (row,col) ranges).  Wave-uniform o-octet -> W on
// scalar pipe.  LDS X read is stride-1 per lane: conflict-free.
__global__ __launch_bounds__(256) void k_mix7(u16* zt_y,
    const u16* __restrict__ Db, const float* __restrict__ W,
    const float* __restrict__ bias){
  __shared__ u32 X[224][64];   // 56 KB
  int tid = threadIdx.x;
  int n0 = blockIdx.x*128;
  int bt = blockIdx.y;               // b*12 + t
  int b = bt / NT, t = bt - b*NT;

  #pragma unroll
  for (int k=0;k<56;k++){
    int i = tid + k*256;
    int r = i >> 6, col = i & 63;    // row r: one row per wave per k -> 256B coalesced
    int s = r >> 5, c = r & 31;      // s wave-uniform
    const u16* src = (s==0) ? zt_y : (Db + (size_t)(s-1)*HBE);
    X[r][col] = *reinterpret_cast<const u32*>(src + ((size_t)(b*NC + c)*NT + t)*NN + n0 + 2*col);
  }
  __syncthreads();

  int lane = tid & 63;
  int og = __builtin_amdgcn_readfirstlane(tid >> 6);   // wave-uniform o-octet

  float a0[8], a1[8];
  #pragma unroll
  for (int oo=0;oo<8;oo++){ float bv = bias[og*8+oo]; a0[oo]=bv; a1[oo]=bv; }

  #pragma unroll
  for (int cc=0; cc<TIN; cc++){
    u32 xp = X[cc][lane];
    float xl = bflo(xp), xh = bfhi(xp);
    #pragma unroll
    for (int oo=0;oo<8;oo++){
      float w = W[(size_t)(og*8+oo)*TIN + cc];   // uniform -> s_load (free pipe)
      a0[oo] += w*xl; a1[oo] += w*xh;
    }
  }

  #pragma unroll
  for (int oo=0;oo<8;oo++){
    u32 pk = (u32)f2bf(a0[oo]) | ((u32)f2bf(a1[oo]) << 16);
    *reinterpret_cast<u32*>(zt_y + ((size_t)(b*NO + og*8+oo)*NT + t)*NN + n0 + 2*lane) = pk;
  }
}

// ---------- final transpose: y[b,o,n,t] = f32(Yb[(b*32+o)*12+t][n]) ----------
__global__ __launch_bounds__(256) void k_out2(const u16* __restrict__ Yb,
                                              float* __restrict__ y){
  __shared__ float tl[256][13];
  int n0 = blockIdx.x*256;
  int bo = blockIdx.y;               // b*32 + o
  int tid = threadIdx.x;
  #pragma unroll
  for (int k=0;k<12;k++)
    tl[tid][k] = bf2f(Yb[((size_t)bo*NT + k)*NN + n0 + tid]);
  __syncthreads();
  float* yp = y + ((size_t)bo*NN + n0)*NT;   // 3072 consecutive floats
  #pragma unroll
  for (int k=0;k<12;k++){
    int i = k*256 + tid;
    yp[i] = tl[i/12][i%12];
  }
}

extern "C" void kernel_launch(void* const* d_in, const int* in_sizes, int n_in,
                              void* d_out, int out_size, void* d_ws, size_t ws_size,
                              hipStream_t stream){
  const float* x    = (const float*)d_in[0];
  const float* a0   = (const float*)d_in[1];
  const float* a1   = (const float*)d_in[2];
  const float* a2   = (const float*)d_in[3];
  const float* W    = (const float*)d_in[4];
  const float* bias = (const float*)d_in[5];
  float* y = (float*)d_out;
  (void)in_sizes; (void)n_in; (void)out_size; (void)ws_size;

  const size_t atB = (size_t)3*NN*NN*2;     // 6.3 MB
  const size_t hB  = HBE*2;                 // 25.2 MB

  char* ws = (char*)d_ws;
  u16* At = (u16*)ws;  ws += atB;
  u16* Zt = (u16*)ws;  ws += hB;            // x in [j][n]; becomes bf16 y after k_mix7
  u16* Db = (u16*)ws;  ws += 6*hB;          // [D1_0 D2_0 D1_1 D2_1 D1_2 D2_2]
  // total = atB + 7*hB = 182.5 MB (exact R4 tier-1 footprint, verified available)

  k_prep_adj<<<dim3(32,32,3), dim3(32,8), 0, stream>>>(a0, a1, a2, At);
  k_prep_x2 <<<dim3(NN/64, NB*NC), 256, 0, stream>>>(x, Zt);

  // D1_g = A_g * Zt   (3 adjacencies in one dispatch, 2304 blocks)
  k_gemm3<0><<<dim3(NJ/128, NN/128, 3), 256, 0, stream>>>(At, Zt, Db);
  // D2_g = A_g * D1_g
  k_gemm3<1><<<dim3(NJ/128, NN/128, 3), 256, 0, stream>>>(At, Zt, Db);

  // y_bf16[(b,o,t)][n] = bias + W.[x | D1_0 D2_0 D1_1 D2_1 D1_2 D2_2]  (over Zt)
  k_mix7<<<dim3(NN/128, NB*NT), 256, 0, stream>>>(Zt, Db, W, bias);

  // y[b,o,n,t] = f32 transpose
  k_out2<<<dim3(NN/256, NB*NO), 256, 0, stream>>>(Zt, y);
}